// Round 6
// baseline (4762.486 us; speedup 1.0000x reference)
//
#include <hip/hip_runtime.h>
#include <hip/hip_bf16.h>
#include <stdint.h>

#define B_ 8
#define S_ 512
#define H_ 1024
#define V_ 32000
#define D_ 768
#define G3H (3*H_)

typedef __bf16 bf16x8_t __attribute__((ext_vector_type(8)));
typedef float f32x4_t __attribute__((ext_vector_type(4)));

__device__ __forceinline__ unsigned short f2bf(float f) {
  unsigned int u = __float_as_uint(f);
  u += 0x7fffu + ((u >> 16) & 1u);      // RNE
  return (unsigned short)(u >> 16);
}
__device__ __forceinline__ float fast_sigmoid(float x) {
  float e = __builtin_amdgcn_exp2f(x * -1.44269504088896340736f);
  return __builtin_amdgcn_rcpf(1.0f + e);
}
__device__ __forceinline__ float fast_tanh(float x) {
  float e = __builtin_amdgcn_exp2f(x * -2.88539008177792681472f);
  return 2.0f * __builtin_amdgcn_rcpf(1.0f + e) - 1.0f;
}

// ---------------- small prep kernels ----------------
__global__ void zero_buf(uint4* __restrict__ p, int n) {
  int i = blockIdx.x * 256 + threadIdx.x;
  if (i < n) p[i] = uint4{0, 0, 0, 0};
}

__global__ void ctx_mean(const float* __restrict__ c, float* __restrict__ ctx) {
  int b = blockIdx.x;
  for (int d = threadIdx.x; d < D_; d += 256) {
    float s = 0.f;
    #pragma unroll
    for (int n = 0; n < 16; ++n) s += c[((size_t)b * 16 + n) * D_ + d];
    ctx[b * D_ + d] = s * (1.0f / 16.0f);
  }
}

// writes fp32 h0 AND tagged bf16 h0 into each layer's slot 0.
// tag: layer0 init consumed at epoch 0 (tag 0); layer1 init consumed at epoch 1 (tag 1).
__global__ void h0_compute(const float* __restrict__ ctx, const float* __restrict__ w,
                           const float* __restrict__ bias, float* __restrict__ h0l,
                           uint32_t* __restrict__ tagw) {
  int o = blockIdx.x * 256 + threadIdx.x;   // 16384 outputs
  int b = o >> 11, row = o & 2047;
  float s = bias[row];
  const float* cw = w + (size_t)row * D_;
  const float* cb = ctx + b * D_;
  for (int d = 0; d < D_; ++d) s += cb[d] * cw[d];
  int layer = row >> 10, u = row & 1023;
  h0l[((size_t)layer * 8 + b) * 1024 + u] = s;
  uint32_t tag = (layer == 0) ? 0u : 1u;
  tagw[(size_t)layer * 16384 + b * 1024 + u] = (tag << 16) | (uint32_t)f2bf(s);
}

__global__ void gather_embed(const int* __restrict__ seq, const float* __restrict__ emb,
                             unsigned short* __restrict__ x) {
  int r = blockIdx.x;                       // 0..4095 = b*512+s
  int idx = seq[r];
  float4 v = ((const float4*)(emb + (size_t)idx * H_))[threadIdx.x];
  ushort4 o;
  o.x = f2bf(v.x); o.y = f2bf(v.y); o.z = f2bf(v.z); o.w = f2bf(v.w);
  ((ushort4*)(x + (size_t)r * H_))[threadIdx.x] = o;
}

__global__ void f32_to_bf16(const float* __restrict__ in, unsigned short* __restrict__ outp, long n4) {
  long i = blockIdx.x * (long)blockDim.x + threadIdx.x;
  long stride = (long)gridDim.x * blockDim.x;
  for (; i < n4; i += stride) {
    float4 v = ((const float4*)in)[i];
    ushort4 o;
    o.x = f2bf(v.x); o.y = f2bf(v.y); o.z = f2bf(v.z); o.w = f2bf(v.w);
    ((ushort4*)outp)[i] = o;
  }
}

// ---------------- bf16 MFMA GEMM: C[M,N] = A[M,K] * B[N,K]^T + bias[N] ----------------
__global__ __launch_bounds__(256) void gemm_bt_bf16(
    const unsigned short* __restrict__ A, const unsigned short* __restrict__ B,
    float* __restrict__ C, const float* __restrict__ bias,
    int M, int N, int K)
{
  __shared__ __align__(16) unsigned short As[128 * 32];
  __shared__ __align__(16) unsigned short Bs[128 * 32];
  const int tid = threadIdx.x;
  const int l = tid & 63;
  const int w = tid >> 6;
  const int wr = w >> 1, wc = w & 1;
  const long row0 = (long)blockIdx.y * 128;
  const long col0 = (long)blockIdx.x * 128;

  f32x4_t acc[4][4];
  #pragma unroll
  for (int m = 0; m < 4; ++m)
    #pragma unroll
    for (int n = 0; n < 4; ++n) acc[m][n] = (f32x4_t)0.0f;

  const int sr = tid >> 2;
  const int sc = (tid & 3) << 3;

  for (int kt = 0; kt < K; kt += 32) {
    __syncthreads();
    uint4 a0 = *(const uint4*)&A[(row0 + sr) * K + kt + sc];
    uint4 a1 = *(const uint4*)&A[(row0 + sr + 64) * K + kt + sc];
    uint4 b0 = *(const uint4*)&B[(col0 + sr) * K + kt + sc];
    uint4 b1 = *(const uint4*)&B[(col0 + sr + 64) * K + kt + sc];
    ((uint4*)As)[tid]       = a0;
    ((uint4*)As)[tid + 256] = a1;
    ((uint4*)Bs)[tid]       = b0;
    ((uint4*)Bs)[tid + 256] = b1;
    __syncthreads();

    bf16x8_t af[4], bfr[4];
    #pragma unroll
    for (int m = 0; m < 4; ++m)
      af[m] = *(const bf16x8_t*)&As[(wr * 64 + m * 16 + (l & 15)) * 32 + (l >> 4) * 8];
    #pragma unroll
    for (int n = 0; n < 4; ++n)
      bfr[n] = *(const bf16x8_t*)&Bs[(wc * 64 + n * 16 + (l & 15)) * 32 + (l >> 4) * 8];
    #pragma unroll
    for (int m = 0; m < 4; ++m)
      #pragma unroll
      for (int n = 0; n < 4; ++n)
        acc[m][n] = __builtin_amdgcn_mfma_f32_16x16x32_bf16(af[m], bfr[n], acc[m][n], 0, 0, 0);
  }

  #pragma unroll
  for (int n = 0; n < 4; ++n) {
    const long col = col0 + wc * 64 + n * 16 + (l & 15);
    const float bv = bias[col];
    #pragma unroll
    for (int m = 0; m < 4; ++m) {
      const long rbase = row0 + wr * 64 + m * 16 + ((l >> 4) << 2);
      #pragma unroll
      for (int v = 0; v < 4; ++v)
        C[(rbase + v) * (long)N + col] = acc[m][n][v] + bv;
    }
  }
}

// ---------------- tagged-word poll (data-as-flag) ----------------
// Each chunk = 8 consecutive tagged u32 (hi16 = epoch tag, lo16 = bf16 value).
// Retries (stale chunks only) until every tag == expected.
template<int NCH>
__device__ __forceinline__ void poll_tagged(const uint32_t* b0, const uint32_t* b1,
                                            uint32_t tag, uint4 (&q0)[NCH], uint4 (&q1)[NCH]) {
  #pragma unroll
  for (int c = 0; c < NCH; ++c) {
    const uint32_t* p = (c < 8) ? (b0 + c * 32) : (b1 + (c - 8) * 32);
    asm volatile("global_load_dwordx4 %0, %2, off sc0 sc1\n\t"
                 "global_load_dwordx4 %1, %2, off offset:16 sc0 sc1"
                 : "=&v"(q0[c]), "=&v"(q1[c]) : "v"(p) : "memory");
  }
  asm volatile("s_waitcnt vmcnt(0)" ::: "memory");
  while (true) {
    uint32_t bad = 0;
    bool st[NCH];
    #pragma unroll
    for (int c = 0; c < NCH; ++c) {
      uint32_t m = (q0[c].x >> 16) ^ tag;
      m |= (q0[c].y >> 16) ^ tag;  m |= (q0[c].z >> 16) ^ tag;  m |= (q0[c].w >> 16) ^ tag;
      m |= (q1[c].x >> 16) ^ tag;  m |= (q1[c].y >> 16) ^ tag;
      m |= (q1[c].z >> 16) ^ tag;  m |= (q1[c].w >> 16) ^ tag;
      st[c] = (m != 0);
      bad |= m;
    }
    if (bad == 0) break;
    __builtin_amdgcn_s_sleep(1);
    #pragma unroll
    for (int c = 0; c < NCH; ++c) {
      if (st[c]) {
        const uint32_t* p = (c < 8) ? (b0 + c * 32) : (b1 + (c - 8) * 32);
        asm volatile("global_load_dwordx4 %0, %2, off sc0 sc1\n\t"
                     "global_load_dwordx4 %1, %2, off offset:16 sc0 sc1"
                     : "=&v"(q0[c]), "=&v"(q1[c]) : "v"(p) : "memory");
      }
    }
    asm volatile("s_waitcnt vmcnt(0)" ::: "memory");
  }
}

__device__ __forceinline__ bf16x8_t pack8(const uint4 a, const uint4 b) {
  uint4 r;
  r.x = (a.x & 0xFFFFu) | (a.y << 16);
  r.y = (a.z & 0xFFFFu) | (a.w << 16);
  r.z = (b.x & 0xFFFFu) | (b.y << 16);
  r.w = (b.z & 0xFFFFu) | (b.w << 16);
  return __builtin_bit_cast(bf16x8_t, r);
}

// ---------------- fused 2-layer persistent GRU, barrier-free ----------------
// 256 blocks x 256 threads. layer = blk>>7, units j0=(blk&127)*8.
// Sync = tagged-word visibility + L1->L0 ack back-pressure. No global barrier.
__device__ __forceinline__ void load_wfrag(const float* __restrict__ W, int j0, int w,
                                           int l15, int lhi, bf16x8_t wf[2][8]) {
  #pragma unroll
  for (int m = 0; m < 2; ++m) {
    const int idx = m * 16 + l15;           // row within the 24
    const int gg = idx >> 3, uu = idx & 7;
    #pragma unroll
    for (int c = 0; c < 8; ++c) {
      f32x4_t v0 = {0.f, 0.f, 0.f, 0.f}, v1 = {0.f, 0.f, 0.f, 0.f};
      if (idx < 24) {
        const float* p = W + (size_t)((gg << 10) + j0 + uu) * 1024
                           + (w << 8) + (c << 5) + (lhi << 3);
        v0 = *(const f32x4_t*)p;
        v1 = *(const f32x4_t*)(p + 4);
      }
      bf16x8_t f;
      f[0] = (__bf16)v0[0]; f[1] = (__bf16)v0[1]; f[2] = (__bf16)v0[2]; f[3] = (__bf16)v0[3];
      f[4] = (__bf16)v1[0]; f[5] = (__bf16)v1[1]; f[6] = (__bf16)v1[2]; f[7] = (__bf16)v1[3];
      wf[m][c] = f;
    }
  }
}

__global__ __launch_bounds__(256, 1) void gru_fused(
    const float* __restrict__ xg,       // [8,512,3072] layer-0 input gates (incl b_ih0)
    const float* __restrict__ w_hh,     // [2,3072,1024]
    const float* __restrict__ w_ih,     // [2,3072,1024]
    const float* __restrict__ b_hh,     // [2,3072]
    const float* __restrict__ b_ih,     // [2,3072]
    const float* __restrict__ h0f,      // [2,8,1024]
    unsigned short* __restrict__ y,     // [8,512,1024] final (layer-1) output bf16
    uint32_t* __restrict__ tagw,        // [2 layers][2 slots][8][1024] tagged u32
    int* __restrict__ acks)             // [128] L1 read-completion epochs
{
  __shared__ __align__(16) float red[4 * 3 * 256];   // 12KB: [wave][slot][16x16 f32]
  const int tid = threadIdx.x;
  const int blk = blockIdx.x;
  const int layer = blk >> 7;
  const int j0 = (blk & 127) * 8;
  const int w = tid >> 6;
  const int l = tid & 63;
  const int l15 = l & 15;
  const int lhi = l >> 4;
  const bool realrow = (l15 < 8);       // rows 8..15 are zero pad: no loads at all

  const float* whh = w_hh + (size_t)layer * G3H * H_;
  const float* bhh = b_hh + (size_t)layer * G3H;
  const float* bih = b_ih + (size_t)layer * G3H;

  bf16x8_t wfh[2][8], wfi[2][8];
  #pragma unroll
  for (int m = 0; m < 2; ++m)
    #pragma unroll
    for (int c = 0; c < 8; ++c) wfi[m][c] = (bf16x8_t)(__bf16)0.0f;
  load_wfrag(whh, j0, w, l15, lhi, wfh);
  if (layer == 1) load_wfrag(w_ih + (size_t)G3H * H_, j0, w, l15, lhi, wfi);

  // per-gate-thread state (tid<64): u = tid&7, b = tid>>3
  const int u = tid & 7;
  const int b = tid >> 3;
  float g_br = 0.f, g_bz = 0.f, g_bnh = 0.f, g_bni = 0.f, hprev = 0.f;
  const float* xgp = nullptr;
  if (tid < 64) {
    float bhr = bhh[j0 + u], bhz = bhh[1024 + j0 + u], bhn = bhh[2048 + j0 + u];
    if (layer == 0) {
      g_br = bhr; g_bz = bhz; g_bnh = bhn;
      xgp = xg + (size_t)(b * S_) * G3H + j0 + u;
    } else {
      g_br = bhr + bih[j0 + u];
      g_bz = bhz + bih[1024 + j0 + u];
      g_bnh = bhn;
      g_bni = bih[2048 + j0 + u];
    }
    hprev = h0f[(size_t)layer * 8192 + b * 1024 + j0 + u];
  }

  uint32_t* const tb0 = tagw;             // layer-0 slots (0/1 at +0/+8192)
  uint32_t* const tb1 = tagw + 16384;     // layer-1 slots
  const int frag_u32 = l15 * 1024 + (w << 8) + (lhi << 3);

  __syncthreads();

  for (int e = 0; e <= S_; ++e) {
    const bool active = (layer == 0) ? (e < S_) : (e >= 1);
    const int t = (layer == 0) ? e : (e - 1);
    const uint32_t tag = (uint32_t)e;

    // L0 back-pressure: don't overwrite y0 slot until all L1 blocks read it.
    if (layer == 0 && active && tid < 128) {
      while (__hip_atomic_load(&acks[tid], __ATOMIC_RELAXED, __HIP_MEMORY_SCOPE_AGENT) < e - 1)
        __builtin_amdgcn_s_sleep(1);
    }

    float xr = 0.f, xz = 0.f, xn = 0.f;
    f32x4_t a0h = (f32x4_t)0.0f, a1h = (f32x4_t)0.0f, a1i = (f32x4_t)0.0f;

    if (active) {
      if (layer == 0) {
        if (tid < 64) {   // issue xg loads early (independent of chain)
          const float* p = xgp + (size_t)t * G3H;
          xr = p[0]; xz = p[1024]; xn = p[2048];
        }
        uint4 q0[8], q1[8];
        #pragma unroll
        for (int c = 0; c < 8; ++c) { q0[c] = uint4{0,0,0,0}; q1[c] = uint4{0,0,0,0}; }
        if (realrow) {
          const uint32_t* hp = tb0 + (e & 1) * 8192 + frag_u32;
          poll_tagged<8>(hp, hp, tag, q0, q1);
        }
        __builtin_amdgcn_sched_barrier(0);
        #pragma unroll
        for (int c = 0; c < 8; ++c) {
          bf16x8_t hf = pack8(q0[c], q1[c]);
          a0h = __builtin_amdgcn_mfma_f32_16x16x32_bf16(wfh[0][c], hf, a0h, 0, 0, 0);
          a1h = __builtin_amdgcn_mfma_f32_16x16x32_bf16(wfh[1][c], hf, a1h, 0, 0, 0);
        }
      } else {
        uint4 q0[16], q1[16];
        #pragma unroll
        for (int c = 0; c < 16; ++c) { q0[c] = uint4{0,0,0,0}; q1[c] = uint4{0,0,0,0}; }
        if (realrow) {
          const uint32_t* yp = tb0 + (e & 1) * 8192 + frag_u32;        // y0_t, tag e
          const uint32_t* hp = tb1 + ((e + 1) & 1) * 8192 + frag_u32;  // h1_{t-1}, tag e
          poll_tagged<16>(yp, hp, tag, q0, q1);
        }
        __builtin_amdgcn_sched_barrier(0);
        #pragma unroll
        for (int c = 0; c < 8; ++c) {
          bf16x8_t yf = pack8(q0[c], q1[c]);
          bf16x8_t hf = pack8(q0[8 + c], q1[8 + c]);
          a0h = __builtin_amdgcn_mfma_f32_16x16x32_bf16(wfh[0][c], hf, a0h, 0, 0, 0);
          a1h = __builtin_amdgcn_mfma_f32_16x16x32_bf16(wfh[1][c], hf, a1h, 0, 0, 0);
          a0h = __builtin_amdgcn_mfma_f32_16x16x32_bf16(wfi[0][c], yf, a0h, 0, 0, 0);
          a1i = __builtin_amdgcn_mfma_f32_16x16x32_bf16(wfi[1][c], yf, a1i, 0, 0, 0);
        }
      }
      // cross-wave K-reduction via LDS (all 3 slots, unconditional)
      *(f32x4_t*)&red[(w * 3 + 0) * 256 + (l << 2)] = a0h;
      *(f32x4_t*)&red[(w * 3 + 1) * 256 + (l << 2)] = a1h;
      *(f32x4_t*)&red[(w * 3 + 2) * 256 + (l << 2)] = a1i;
    }
    __syncthreads();   // (1) reduction barrier — uniform; also = "block reads done"

    // L1 posts read-completion (frees L0 to overwrite y0 slot)
    if (layer == 1 && active && tid == 0)
      __hip_atomic_store(&acks[blk & 127], e, __ATOMIC_RELAXED, __HIP_MEMORY_SCOPE_AGENT);

    if (active && tid < 64) {
      const int base0 = (((u >> 2) << 4 | b) << 2) + (u & 3);   // tile row u
      const int base1 = base0 + 128;                            // tile row 8+u
      float aR = 0.f, aZ = 0.f, aNh = 0.f, aNi = 0.f;
      #pragma unroll
      for (int ww = 0; ww < 4; ++ww) {
        aR  += red[ww * 768 + base0];
        aZ  += red[ww * 768 + base1];
        aNh += red[ww * 768 + 256 + base0];
        aNi += red[ww * 768 + 512 + base0];
      }
      float r, z, n;
      if (layer == 0) {
        r = fast_sigmoid(xr + g_br + aR);
        z = fast_sigmoid(xz + g_bz + aZ);
        n = fast_tanh(xn + r * (aNh + g_bnh));
      } else {
        r = fast_sigmoid(aR + g_br);
        z = fast_sigmoid(aZ + g_bz);
        n = fast_tanh(aNi + g_bni + r * (aNh + g_bnh));
      }
      hprev = (1.0f - z) * n + z * hprev;
      unsigned short hv16 = f2bf(hprev);
      // tagged self-validating store: tag e+1 in hi16, value in lo16
      uint32_t word = ((uint32_t)(e + 1) << 16) | (uint32_t)hv16;
      uint32_t* hdst = (layer == 0)
          ? (tb0 + ((e + 1) & 1) * 8192 + b * 1024 + j0 + u)
          : (tb1 + (e & 1) * 8192 + b * 1024 + j0 + u);
      if (layer == 1)
        y[(((size_t)(b * S_ + t)) << 10) + j0 + u] = hv16;   // cached store (GEMM reads)
      asm volatile("global_store_dword %0, %1, off sc0 sc1"
                   :: "v"(hdst), "v"(word) : "memory");
    }
    __syncthreads();   // (2) protects red across epochs (wave0 reads red above)
  }
}

// ---------------- launch ----------------
extern "C" void kernel_launch(void* const* d_in, const int* in_sizes, int n_in,
                              void* d_out, int out_size, void* d_ws, size_t ws_size,
                              hipStream_t stream) {
  (void)in_sizes; (void)n_in; (void)out_size; (void)ws_size;
  const float* concepts = (const float*)d_in[0];
  const int*   seq      = (const int*)d_in[1];
  const float* emb      = (const float*)d_in[2];
  const float* w_ih     = (const float*)d_in[3];
  const float* w_hh     = (const float*)d_in[4];
  const float* b_ih     = (const float*)d_in[5];
  const float* b_hh     = (const float*)d_in[6];
  const float* fc_w     = (const float*)d_in[7];
  const float* fc_b     = (const float*)d_in[8];
  const float* c2h_w    = (const float*)d_in[9];
  const float* c2h_b    = (const float*)d_in[10];
  float* out = (float*)d_out;

  char* ws = (char*)d_ws;
  size_t off = 0;
  auto alloc = [&](size_t bytes) {
    char* p = ws + off;
    off += (bytes + 255) & ~(size_t)255;
    return p;
  };
  unsigned short* xy   = (unsigned short*)alloc((size_t)B_ * S_ * H_ * 2);   // x bf16, then y
  float*          xg   = (float*)alloc((size_t)B_ * S_ * G3H * 4);           // layer-0 input gates
  unsigned short* wihb = (unsigned short*)alloc((size_t)G3H * H_ * 2);       // layer-0 W_ih bf16
  unsigned short* fcwb = (unsigned short*)alloc((size_t)V_ * H_ * 2);
  float*          ctx  = (float*)alloc((size_t)B_ * D_ * 4);
  float*          h0l  = (float*)alloc((size_t)2 * B_ * H_ * 4);
  uint32_t*       tagw = (uint32_t*)alloc((size_t)2 * 2 * 8 * 1024 * 4);     // 128KB tagged h
  int*            acks = (int*)alloc((size_t)128 * 4);

  // acks MUST be zeroed every launch (stale acks from a prior replay would
  // break WAR back-pressure). tagw slot-0 rewritten by h0_compute; slot-1
  // leftovers are benign (deterministic identical values, or 0xAA tag -> spin).
  zero_buf<<<dim3(1), dim3(256), 0, stream>>>((uint4*)acks, 128 / 4);
  ctx_mean<<<dim3(8), dim3(256), 0, stream>>>(concepts, ctx);
  h0_compute<<<dim3(64), dim3(256), 0, stream>>>(ctx, c2h_w, c2h_b, h0l, tagw);
  gather_embed<<<dim3(B_ * S_), dim3(256), 0, stream>>>(seq, emb, xy);
  f32_to_bf16<<<dim3(1024), dim3(256), 0, stream>>>(w_ih, wihb, (long)G3H * H_ / 4);
  f32_to_bf16<<<dim3(2048), dim3(256), 0, stream>>>(fc_w, fcwb, (long)V_ * H_ / 4);

  // layer-0 input gates (GEMM)
  gemm_bt_bf16<<<dim3(G3H / 128, (B_ * S_) / 128), dim3(256), 0, stream>>>(
      xy, wihb, xg, b_ih, B_ * S_, G3H, H_);

  // fused 2-layer skewed recurrence (barrier-free, tagged sync)
  gru_fused<<<dim3(256), dim3(256), 0, stream>>>(
      xg, w_hh, w_ih, b_hh, b_ih, h0l, xy, tagw, acks);

  // logits
  gemm_bt_bf16<<<dim3(V_ / 128, (B_ * S_) / 128), dim3(256), 0, stream>>>(
      xy, fcwb, out, fc_b, B_ * S_, V_, H_);
}

// Round 7
// 2505.410 us; speedup vs baseline: 1.9009x; 1.9009x over previous
//
#include <hip/hip_runtime.h>
#include <hip/hip_bf16.h>
#include <stdint.h>

#define B_ 8
#define S_ 512
#define H_ 1024
#define V_ 32000
#define D_ 768
#define G3H (3*H_)

typedef __bf16 bf16x8_t __attribute__((ext_vector_type(8)));
typedef float f32x4_t __attribute__((ext_vector_type(4)));

__device__ __forceinline__ unsigned short f2bf(float f) {
  unsigned int u = __float_as_uint(f);
  u += 0x7fffu + ((u >> 16) & 1u);      // RNE
  return (unsigned short)(u >> 16);
}
__device__ __forceinline__ float fast_sigmoid(float x) {
  float e = __builtin_amdgcn_exp2f(x * -1.44269504088896340736f);
  return __builtin_amdgcn_rcpf(1.0f + e);
}
__device__ __forceinline__ float fast_tanh(float x) {
  float e = __builtin_amdgcn_exp2f(x * -2.88539008177792681472f);
  return 2.0f * __builtin_amdgcn_rcpf(1.0f + e) - 1.0f;
}

// ---------------- small prep kernels ----------------
__global__ void zero_buf(uint4* __restrict__ p, int n) {
  int i = blockIdx.x * 256 + threadIdx.x;
  if (i < n) p[i] = uint4{0, 0, 0, 0};
}

__global__ void ctx_mean(const float* __restrict__ c, float* __restrict__ ctx) {
  int b = blockIdx.x;
  for (int d = threadIdx.x; d < D_; d += 256) {
    float s = 0.f;
    #pragma unroll
    for (int n = 0; n < 16; ++n) s += c[((size_t)b * 16 + n) * D_ + d];
    ctx[b * D_ + d] = s * (1.0f / 16.0f);
  }
}

// writes fp32 h0 (register h_prev init) AND bf16 h0 into each layer's slot 0
// hb layout: [L0: 3 slots][L1: 2 slots], each slot = [8][1024] u16.
__global__ void h0_compute(const float* __restrict__ ctx, const float* __restrict__ w,
                           const float* __restrict__ bias, float* __restrict__ h0l,
                           unsigned short* __restrict__ hb) {
  int o = blockIdx.x * 256 + threadIdx.x;   // 16384 outputs
  int b = o >> 11, row = o & 2047;
  float s = bias[row];
  const float* cw = w + (size_t)row * D_;
  const float* cb = ctx + b * D_;
  for (int d = 0; d < D_; ++d) s += cb[d] * cw[d];
  int layer = row >> 10, u = row & 1023;
  h0l[((size_t)layer * 8 + b) * 1024 + u] = s;
  hb[(layer ? 24576 : 0) + b * 1024 + u] = f2bf(s);
}

__global__ void gather_embed(const int* __restrict__ seq, const float* __restrict__ emb,
                             unsigned short* __restrict__ x) {
  int r = blockIdx.x;                       // 0..4095 = b*512+s
  int idx = seq[r];
  float4 v = ((const float4*)(emb + (size_t)idx * H_))[threadIdx.x];
  ushort4 o;
  o.x = f2bf(v.x); o.y = f2bf(v.y); o.z = f2bf(v.z); o.w = f2bf(v.w);
  ((ushort4*)(x + (size_t)r * H_))[threadIdx.x] = o;
}

__global__ void f32_to_bf16(const float* __restrict__ in, unsigned short* __restrict__ outp, long n4) {
  long i = blockIdx.x * (long)blockDim.x + threadIdx.x;
  long stride = (long)gridDim.x * blockDim.x;
  for (; i < n4; i += stride) {
    float4 v = ((const float4*)in)[i];
    ushort4 o;
    o.x = f2bf(v.x); o.y = f2bf(v.y); o.z = f2bf(v.z); o.w = f2bf(v.w);
    ((ushort4*)outp)[i] = o;
  }
}

// ---------------- bf16 MFMA GEMM: C[M,N] = A[M,K] * B[N,K]^T + bias[N] ----------------
__global__ __launch_bounds__(256) void gemm_bt_bf16(
    const unsigned short* __restrict__ A, const unsigned short* __restrict__ B,
    float* __restrict__ C, const float* __restrict__ bias,
    int M, int N, int K)
{
  __shared__ __align__(16) unsigned short As[128 * 32];
  __shared__ __align__(16) unsigned short Bs[128 * 32];
  const int tid = threadIdx.x;
  const int l = tid & 63;
  const int w = tid >> 6;
  const int wr = w >> 1, wc = w & 1;
  const long row0 = (long)blockIdx.y * 128;
  const long col0 = (long)blockIdx.x * 128;

  f32x4_t acc[4][4];
  #pragma unroll
  for (int m = 0; m < 4; ++m)
    #pragma unroll
    for (int n = 0; n < 4; ++n) acc[m][n] = (f32x4_t)0.0f;

  const int sr = tid >> 2;
  const int sc = (tid & 3) << 3;

  for (int kt = 0; kt < K; kt += 32) {
    __syncthreads();
    uint4 a0 = *(const uint4*)&A[(row0 + sr) * K + kt + sc];
    uint4 a1 = *(const uint4*)&A[(row0 + sr + 64) * K + kt + sc];
    uint4 b0 = *(const uint4*)&B[(col0 + sr) * K + kt + sc];
    uint4 b1 = *(const uint4*)&B[(col0 + sr + 64) * K + kt + sc];
    ((uint4*)As)[tid]       = a0;
    ((uint4*)As)[tid + 256] = a1;
    ((uint4*)Bs)[tid]       = b0;
    ((uint4*)Bs)[tid + 256] = b1;
    __syncthreads();

    bf16x8_t af[4], bfr[4];
    #pragma unroll
    for (int m = 0; m < 4; ++m)
      af[m] = *(const bf16x8_t*)&As[(wr * 64 + m * 16 + (l & 15)) * 32 + (l >> 4) * 8];
    #pragma unroll
    for (int n = 0; n < 4; ++n)
      bfr[n] = *(const bf16x8_t*)&Bs[(wc * 64 + n * 16 + (l & 15)) * 32 + (l >> 4) * 8];
    #pragma unroll
    for (int m = 0; m < 4; ++m)
      #pragma unroll
      for (int n = 0; n < 4; ++n)
        acc[m][n] = __builtin_amdgcn_mfma_f32_16x16x32_bf16(af[m], bfr[n], acc[m][n], 0, 0, 0);
  }

  #pragma unroll
  for (int n = 0; n < 4; ++n) {
    const long col = col0 + wc * 64 + n * 16 + (l & 15);
    const float bv = bias[col];
    #pragma unroll
    for (int m = 0; m < 4; ++m) {
      const long rbase = row0 + wr * 64 + m * 16 + ((l >> 4) << 2);
      #pragma unroll
      for (int v = 0; v < 4; ++v)
        C[(rbase + v) * (long)N + col] = acc[m][n][v] + bv;
    }
  }
}

// ---------------- fused 2-layer persistent GRU (decoupled flags) ----------------
// 128 blocks x 256 threads. layer = blk>>6, units j0=(blk&63)*16 (48 W-rows).
// L0 h/y0: 3-slot buffer (2 epochs of WAR slack). L1 h1: 2-slot ping-pong.
// Flags: fl[block] = completed epochs. Waves 1-3 poll; wave 0 produces.
__device__ __forceinline__ void load_wfrag3(const float* __restrict__ W, int j0, int w,
                                            int l15, int lhi, bf16x8_t wf[3][8]) {
  #pragma unroll
  for (int m = 0; m < 3; ++m) {
    const float* pr = W + (size_t)((m << 10) + j0 + l15) * 1024 + (w << 8) + (lhi << 3);
    #pragma unroll
    for (int c = 0; c < 8; ++c) {
      f32x4_t v0 = *(const f32x4_t*)(pr + (c << 5));
      f32x4_t v1 = *(const f32x4_t*)(pr + (c << 5) + 4);
      bf16x8_t f;
      f[0] = (__bf16)v0[0]; f[1] = (__bf16)v0[1]; f[2] = (__bf16)v0[2]; f[3] = (__bf16)v0[3];
      f[4] = (__bf16)v1[0]; f[5] = (__bf16)v1[1]; f[6] = (__bf16)v1[2]; f[7] = (__bf16)v1[3];
      wf[m][c] = f;
    }
  }
}

__global__ __launch_bounds__(256, 1) void gru_fused(
    const float* __restrict__ xg,       // [8,512,3072] layer-0 input gates (incl b_ih0)
    const float* __restrict__ w_hh,     // [2,3072,1024]
    const float* __restrict__ w_ih,     // [2,3072,1024]
    const float* __restrict__ b_hh,     // [2,3072]
    const float* __restrict__ b_ih,     // [2,3072]
    const float* __restrict__ h0f,      // [2,8,1024]
    unsigned short* __restrict__ y,     // [8,512,1024] final output bf16
    unsigned short* __restrict__ hb,    // [3 + 2 slots][8][1024] u16
    int* __restrict__ fl)               // [128*32] flags
{
  __shared__ __align__(16) float red[4 * 4 * 256];   // 16KB: [wave][tile][16x16 f32]
  const int tid = threadIdx.x;
  const int blk = blockIdx.x;
  const int layer = blk >> 6;
  const int j0 = (blk & 63) << 4;       // 16 units per block
  const int w = tid >> 6;
  const int l = tid & 63;
  const int l15 = l & 15;
  const int lhi = l >> 4;
  const bool realrow = (l15 < 8);

  // ---- weights in registers: 3 gate tiles x 8 K-frags (per wave K-quarter) ----
  bf16x8_t wfh[3][8], wfi[3][8];
  #pragma unroll
  for (int m = 0; m < 3; ++m)
    #pragma unroll
    for (int c = 0; c < 8; ++c) wfi[m][c] = (bf16x8_t)(__bf16)0.0f;
  load_wfrag3(w_hh + (size_t)layer * G3H * H_, j0, w, l15, lhi, wfh);
  if (layer == 1) load_wfrag3(w_ih + (size_t)G3H * H_, j0, w, l15, lhi, wfi);

  // ---- gate-thread state (tid<64): unit pair up=tid&7 (units 2up,2up+1), batch b=tid>>3 ----
  const int up = tid & 7;
  const int b = tid >> 3;
  float gbr0 = 0.f, gbz0 = 0.f, gbnh0 = 0.f, gbni0 = 0.f, hp0 = 0.f;
  float gbr1 = 0.f, gbz1 = 0.f, gbnh1 = 0.f, gbni1 = 0.f, hp1 = 0.f;
  const float* xgp = nullptr;
  if (tid < 64) {
    const float* bhh_l = b_hh + (size_t)layer * G3H;
    const float* bih_l = b_ih + (size_t)layer * G3H;
    const int uj = j0 + 2 * up;
    float bhr0 = bhh_l[uj],     bhz0 = bhh_l[1024 + uj],     bhn0 = bhh_l[2048 + uj];
    float bhr1 = bhh_l[uj + 1], bhz1 = bhh_l[1024 + uj + 1], bhn1 = bhh_l[2048 + uj + 1];
    if (layer == 0) {
      gbr0 = bhr0; gbz0 = bhz0; gbnh0 = bhn0;
      gbr1 = bhr1; gbz1 = bhz1; gbnh1 = bhn1;
      xgp = xg + (size_t)(b * S_) * G3H + uj;
    } else {
      gbr0 = bhr0 + bih_l[uj];     gbz0 = bhz0 + bih_l[1024 + uj];
      gbnh0 = bhn0;                gbni0 = bih_l[2048 + uj];
      gbr1 = bhr1 + bih_l[uj + 1]; gbz1 = bhz1 + bih_l[1024 + uj + 1];
      gbnh1 = bhn1;                gbni1 = bih_l[2048 + uj + 1];
    }
    float2 h2 = *(const float2*)&h0f[(size_t)layer * 8192 + b * 1024 + uj];
    hp0 = h2.x; hp1 = h2.y;
  }

  unsigned short* const hb0 = hb;            // 3 slots (L0 h / y0)
  unsigned short* const hb1 = hb + 24576;    // 2 slots (L1 h)
  const int frag = l15 * 1024 + (w << 8) + (lhi << 3);

  for (int e = 0; e <= S_; ++e) {
    const bool active = (layer == 0) ? (e < S_) : (e >= 1);
    const int t = (layer == 0) ? e : (e - 1);
    const int s3 = e % 3;

    // ---- poll (waves 1-3 only; wave 0 is still finishing previous epoch tail) ----
    if (tid >= 64 && tid < 192) {
      const int idx = tid - 64;   // block id 0..127
      const int thr = (idx < 64) ? e : ((layer == 0) ? (e - 1) : e);
      while (__hip_atomic_load(&fl[idx * 32], __ATOMIC_RELAXED, __HIP_MEMORY_SCOPE_AGENT) < thr)
        __builtin_amdgcn_s_sleep(1);
    }
    __syncthreads();   // (A) flags confirmed + epoch join (red WAR-safe)

    f32x4_t accR = (f32x4_t)0.0f, accZ = (f32x4_t)0.0f;
    f32x4_t accNh = (f32x4_t)0.0f, accNi = (f32x4_t)0.0f;
    float2 xr2 = {0.f, 0.f}, xz2 = {0.f, 0.f}, xn2 = {0.f, 0.f};

    if (active) {
      f32x4_t hv[8], yv[8];
      #pragma unroll
      for (int c = 0; c < 8; ++c) { hv[c] = (f32x4_t)0.0f; yv[c] = (f32x4_t)0.0f; }
      if (realrow) {
        const unsigned short* hp = (layer == 0) ? (hb0 + s3 * 8192 + frag)
                                                : (hb1 + ((e + 1) & 1) * 8192 + frag);
        #pragma unroll
        for (int c = 0; c < 8; ++c)
          asm volatile("global_load_dwordx4 %0, %1, off offset:%2 sc0 sc1"
                       : "=v"(hv[c]) : "v"(hp), "i"(c * 64) : "memory");
        if (layer == 1) {
          const unsigned short* yp = hb0 + s3 * 8192 + frag;   // y0_{e-1}
          #pragma unroll
          for (int c = 0; c < 8; ++c)
            asm volatile("global_load_dwordx4 %0, %1, off offset:%2 sc0 sc1"
                         : "=v"(yv[c]) : "v"(yp), "i"(c * 64) : "memory");
        }
      }
      if (layer == 0 && tid < 64) {
        const float* p = xgp + (size_t)t * G3H;
        xr2 = *(const float2*)p;
        xz2 = *(const float2*)(p + 1024);
        xn2 = *(const float2*)(p + 2048);
      }
      asm volatile("s_waitcnt vmcnt(0)" ::: "memory");
      __builtin_amdgcn_sched_barrier(0);

      #pragma unroll
      for (int c = 0; c < 8; ++c) {
        bf16x8_t hf = __builtin_bit_cast(bf16x8_t, hv[c]);
        accR  = __builtin_amdgcn_mfma_f32_16x16x32_bf16(wfh[0][c], hf, accR,  0, 0, 0);
        accZ  = __builtin_amdgcn_mfma_f32_16x16x32_bf16(wfh[1][c], hf, accZ,  0, 0, 0);
        accNh = __builtin_amdgcn_mfma_f32_16x16x32_bf16(wfh[2][c], hf, accNh, 0, 0, 0);
      }
      if (layer == 1) {
        #pragma unroll
        for (int c = 0; c < 8; ++c) {
          bf16x8_t yf = __builtin_bit_cast(bf16x8_t, yv[c]);
          accR  = __builtin_amdgcn_mfma_f32_16x16x32_bf16(wfi[0][c], yf, accR,  0, 0, 0);
          accZ  = __builtin_amdgcn_mfma_f32_16x16x32_bf16(wfi[1][c], yf, accZ,  0, 0, 0);
          accNi = __builtin_amdgcn_mfma_f32_16x16x32_bf16(wfi[2][c], yf, accNi, 0, 0, 0);
        }
      }
      *(f32x4_t*)&red[(w * 4 + 0) * 256 + (l << 2)] = accR;
      *(f32x4_t*)&red[(w * 4 + 1) * 256 + (l << 2)] = accZ;
      *(f32x4_t*)&red[(w * 4 + 2) * 256 + (l << 2)] = accNh;
      *(f32x4_t*)&red[(w * 4 + 3) * 256 + (l << 2)] = accNi;
    }
    __syncthreads();   // (B) red ready

    if (active && tid < 64) {
      const int u0 = 2 * up, u1 = 2 * up + 1;
      const int i0 = ((((u0 >> 2) << 4) | b) << 2) + (u0 & 3);
      const int i1 = ((((u1 >> 2) << 4) | b) << 2) + (u1 & 3);
      float aR0 = 0.f, aZ0 = 0.f, aNh0 = 0.f, aNi0 = 0.f;
      float aR1 = 0.f, aZ1 = 0.f, aNh1 = 0.f, aNi1 = 0.f;
      #pragma unroll
      for (int ww = 0; ww < 4; ++ww) {
        const float* rw = red + ww * 1024;
        aR0  += rw[i0];        aR1  += rw[i1];
        aZ0  += rw[256 + i0];  aZ1  += rw[256 + i1];
        aNh0 += rw[512 + i0];  aNh1 += rw[512 + i1];
        aNi0 += rw[768 + i0];  aNi1 += rw[768 + i1];
      }
      float r0, z0, n0, r1, z1, n1;
      if (layer == 0) {
        r0 = fast_sigmoid(xr2.x + gbr0 + aR0);
        z0 = fast_sigmoid(xz2.x + gbz0 + aZ0);
        n0 = fast_tanh(xn2.x + r0 * (aNh0 + gbnh0));
        r1 = fast_sigmoid(xr2.y + gbr1 + aR1);
        z1 = fast_sigmoid(xz2.y + gbz1 + aZ1);
        n1 = fast_tanh(xn2.y + r1 * (aNh1 + gbnh1));
      } else {
        r0 = fast_sigmoid(aR0 + gbr0);
        z0 = fast_sigmoid(aZ0 + gbz0);
        n0 = fast_tanh(aNi0 + gbni0 + r0 * (aNh0 + gbnh0));
        r1 = fast_sigmoid(aR1 + gbr1);
        z1 = fast_sigmoid(aZ1 + gbz1);
        n1 = fast_tanh(aNi1 + gbni1 + r1 * (aNh1 + gbnh1));
      }
      hp0 = (1.0f - z0) * n0 + z0 * hp0;
      hp1 = (1.0f - z1) * n1 + z1 * hp1;
      uint32_t word = ((uint32_t)f2bf(hp1) << 16) | (uint32_t)f2bf(hp0);
      unsigned short* hdst = (layer == 0)
          ? (hb0 + ((e + 1) % 3) * 8192 + b * 1024 + j0 + 2 * up)
          : (hb1 + (e & 1) * 8192 + b * 1024 + j0 + 2 * up);
      if (layer == 1)
        *(uint32_t*)&y[(((size_t)(b * S_ + t)) << 10) + j0 + 2 * up] = word;
      asm volatile("global_store_dword %0, %1, off sc0 sc1"
                   :: "v"(hdst), "v"(word) : "memory");
    }
    // drain (wave 0's h stores; trivial for waves 1-3), then release
    asm volatile("s_waitcnt vmcnt(0)" ::: "memory");
    if (tid == 0)
      __hip_atomic_store(&fl[blk * 32], e + 1,
                         __ATOMIC_RELAXED, __HIP_MEMORY_SCOPE_AGENT);
  }
}

// ---------------- launch ----------------
extern "C" void kernel_launch(void* const* d_in, const int* in_sizes, int n_in,
                              void* d_out, int out_size, void* d_ws, size_t ws_size,
                              hipStream_t stream) {
  (void)in_sizes; (void)n_in; (void)out_size; (void)ws_size;
  const float* concepts = (const float*)d_in[0];
  const int*   seq      = (const int*)d_in[1];
  const float* emb      = (const float*)d_in[2];
  const float* w_ih     = (const float*)d_in[3];
  const float* w_hh     = (const float*)d_in[4];
  const float* b_ih     = (const float*)d_in[5];
  const float* b_hh     = (const float*)d_in[6];
  const float* fc_w     = (const float*)d_in[7];
  const float* fc_b     = (const float*)d_in[8];
  const float* c2h_w    = (const float*)d_in[9];
  const float* c2h_b    = (const float*)d_in[10];
  float* out = (float*)d_out;

  char* ws = (char*)d_ws;
  size_t off = 0;
  auto alloc = [&](size_t bytes) {
    char* p = ws + off;
    off += (bytes + 255) & ~(size_t)255;
    return p;
  };
  unsigned short* xy   = (unsigned short*)alloc((size_t)B_ * S_ * H_ * 2);   // x bf16, then y
  float*          xg   = (float*)alloc((size_t)B_ * S_ * G3H * 4);           // layer-0 input gates
  unsigned short* wihb = (unsigned short*)alloc((size_t)G3H * H_ * 2);       // layer-0 W_ih bf16
  unsigned short* fcwb = (unsigned short*)alloc((size_t)V_ * H_ * 2);
  float*          ctx  = (float*)alloc((size_t)B_ * D_ * 4);
  float*          h0l  = (float*)alloc((size_t)2 * B_ * H_ * 4);
  unsigned short* hb   = (unsigned short*)alloc((size_t)5 * 8 * 1024 * 2);   // 80KB (3+2 slots)
  int*            fl   = (int*)alloc((size_t)128 * 32 * 4);                  // 16KB flags

  // flags MUST be zeroed every launch (monotone counters)
  zero_buf<<<dim3(4), dim3(256), 0, stream>>>((uint4*)fl, 128 * 32 / 4);
  ctx_mean<<<dim3(8), dim3(256), 0, stream>>>(concepts, ctx);
  h0_compute<<<dim3(64), dim3(256), 0, stream>>>(ctx, c2h_w, c2h_b, h0l, hb);
  gather_embed<<<dim3(B_ * S_), dim3(256), 0, stream>>>(seq, emb, xy);
  f32_to_bf16<<<dim3(1024), dim3(256), 0, stream>>>(w_ih, wihb, (long)G3H * H_ / 4);
  f32_to_bf16<<<dim3(2048), dim3(256), 0, stream>>>(fc_w, fcwb, (long)V_ * H_ / 4);

  // layer-0 input gates (GEMM)
  gemm_bt_bf16<<<dim3(G3H / 128, (B_ * S_) / 128), dim3(256), 0, stream>>>(
      xy, wihb, xg, b_ih, B_ * S_, G3H, H_);

  // fused 2-layer skewed recurrence (decoupled flag sync)
  gru_fused<<<dim3(128), dim3(256), 0, stream>>>(
      xg, w_hh, w_ih, b_hh, b_ih, h0l, xy, hb, fl);

  // logits
  gemm_bt_bf16<<<dim3(V_ / 128, (B_ * S_) / 128), dim3(256), 0, stream>>>(
      xy, fcwb, out, fc_b, B_ * S_, V_, H_);
}